// Round 2
// baseline (39.437 us; speedup 1.0000x reference)
//
#include <hip/hip_runtime.h>
#include <hip/hip_bf16.h>

#define B_ 8
#define N_ 1024
#define D_ 256
#define M_ (B_ * N_)   // 8192

typedef __attribute__((ext_vector_type(8))) short bf16x8;
typedef __attribute__((ext_vector_type(8))) unsigned short u16x8;
typedef __attribute__((ext_vector_type(4))) float f32x4;
typedef __attribute__((ext_vector_type(4))) int i32x4;

__device__ __forceinline__ unsigned short f2bf(float f) {
    unsigned int u = __float_as_uint(f);
    u += 0x7fffu + ((u >> 16) & 1u);   // RNE to bf16
    return (unsigned short)(u >> 16);
}
// HW packed convert: 2 f32 -> 2 bf16 (RNE), 1 instruction
__device__ __forceinline__ unsigned int cvtpk(float lo, float hi) {
    unsigned int r;
    asm("v_cvt_pk_bf16_f32 %0, %1, %2" : "=v"(r) : "v"(lo), "v"(hi));
    return r;
}
__device__ __forceinline__ bf16x8 load8_f32_bf(const float* __restrict__ p) {
    const float4* q = (const float4*)p;
    float4 u = q[0], v = q[1];
    union { unsigned int u4[4]; bf16x8 v8; } c;
    c.u4[0] = cvtpk(u.x, u.y); c.u4[1] = cvtpk(u.z, u.w);
    c.u4[2] = cvtpk(v.x, v.y); c.u4[3] = cvtpk(v.z, v.w);
    return c.v8;
}

// ---- k1: h = x @ W^T -> hT; fused s1/s2; XCD-pinned: bid&7 = batch ---------
__global__ __launch_bounds__(512) void k_hgemm(const float* __restrict__ x,
        const float* __restrict__ W,
        const float* __restrict__ a1, const float* __restrict__ a2,
        unsigned short* __restrict__ hT,
        float* __restrict__ s1, float* __restrict__ s2) {
    __shared__ unsigned short xs[32 * 256];        // 16 KB, XOR-swizzled rows
    __shared__ unsigned short tls[8][32][40];      // 20 KB h tile, 16B-aligned rows
    __shared__ float spart[8][32][9];              // 9 KB s1/s2 partials per wave
    const int tid = threadIdx.x;
    const int wslot = tid >> 6, lane = tid & 63;
    // XCD-pinned remap: blocks with bid&7==b handle batch b -> hT[b] lands in XCD-b L2
    const int mt = (blockIdx.x & 7) * 32 + (blockIdx.x >> 3);   // 0..255
    const int m0 = mt * 32, n0 = wslot * 32;       // 8 waves = 8 o-tiles
    char* xc = (char*)xs;

    // stage x tile: 32 rows x 256 cols f32 -> bf16, swizzled
    // NT loads: x is streamed exactly once -> don't evict W/hT from L2
    {
        const int row = tid >> 4, colg = (tid & 15) * 16;
        const f32x4* xp = (const f32x4*)(x + (m0 + row) * D_ + colg);
        f32x4 f0 = __builtin_nontemporal_load(xp);
        f32x4 f1 = __builtin_nontemporal_load(xp + 1);
        f32x4 f2 = __builtin_nontemporal_load(xp + 2);
        f32x4 f3 = __builtin_nontemporal_load(xp + 3);
        union { unsigned int u4[8]; u16x8 v8[2]; } c;
        c.u4[0] = cvtpk(f0[0], f0[1]); c.u4[1] = cvtpk(f0[2], f0[3]);
        c.u4[2] = cvtpk(f1[0], f1[1]); c.u4[3] = cvtpk(f1[2], f1[3]);
        c.u4[4] = cvtpk(f2[0], f2[1]); c.u4[5] = cvtpk(f2[2], f2[3]);
        c.u4[6] = cvtpk(f3[0], f3[1]); c.u4[7] = cvtpk(f3[2], f3[3]);
        const int base = row * 512 + colg * 2, sw = (row & 7) << 4;
        *(u16x8*)(xc + ((base) ^ sw))      = c.v8[0];
        *(u16x8*)(xc + ((base + 16) ^ sw)) = c.v8[1];
    }
    __syncthreads();

    const int r = lane & 15, kg = lane >> 4;
    const int sw = (r & 7) << 4;
    const int abase0 = r * 512, abase1 = (16 + r) * 512;
    const float* wb0 = W + (n0 + r) * D_ + kg * 8;
    const float* wb1 = wb0 + 16 * D_;
    f32x4 z = {0.f, 0.f, 0.f, 0.f};
    f32x4 acc00 = z, acc01 = z, acc10 = z, acc11 = z;
    bf16x8 nb0 = load8_f32_bf(wb0);
    bf16x8 nb1 = load8_f32_bf(wb1);
    #pragma unroll
    for (int d0 = 0; d0 < D_; d0 += 32) {
        const int kb = (d0 + kg * 8) * 2;
        bf16x8 a0 = *(const bf16x8*)(xc + ((abase0 + kb) ^ sw));
        bf16x8 a1f = *(const bf16x8*)(xc + ((abase1 + kb) ^ sw));
        bf16x8 b0 = nb0, b1 = nb1;
        if (d0 + 32 < D_) {
            nb0 = load8_f32_bf(wb0 + d0 + 32);
            nb1 = load8_f32_bf(wb1 + d0 + 32);
        }
        acc00 = __builtin_amdgcn_mfma_f32_16x16x32_bf16(a0, b0, acc00, 0, 0, 0);
        acc01 = __builtin_amdgcn_mfma_f32_16x16x32_bf16(a0, b1, acc01, 0, 0, 0);
        acc10 = __builtin_amdgcn_mfma_f32_16x16x32_bf16(a1f, b0, acc10, 0, 0, 0);
        acc11 = __builtin_amdgcn_mfma_f32_16x16x32_bf16(a1f, b1, acc11, 0, 0, 0);
    }
    const int col = lane & 15, rb = (lane >> 4) * 4;
    f32x4 accs[2][2] = {{acc00, acc01}, {acc10, acc11}};
    #pragma unroll
    for (int rt = 0; rt < 2; ++rt)
      #pragma unroll
      for (int ct = 0; ct < 2; ++ct)
        #pragma unroll
        for (int q = 0; q < 4; ++q)
            tls[wslot][rt * 16 + rb + q][ct * 16 + col] = f2bf(accs[rt][ct][q]);
    __syncthreads();

    // ---- s1/s2 partials via MFMA: A = h rows (from tls), B = [a1;a2] 8 rows -
    {
        bf16x8 bfr = {0, 0, 0, 0, 0, 0, 0, 0};
        if (r < 8) {
            const float* ap = (r < 4 ? a1 + r * D_ : a2 + (r - 4) * D_) + n0 + kg * 8;
            bfr = load8_f32_bf(ap);
        }
        bf16x8 af0 = *(const bf16x8*)&tls[wslot][r][kg * 8];
        bf16x8 af1 = *(const bf16x8*)&tls[wslot][16 + r][kg * 8];
        f32x4 s0 = __builtin_amdgcn_mfma_f32_16x16x32_bf16(af0, bfr, z, 0, 0, 0);
        f32x4 s1v = __builtin_amdgcn_mfma_f32_16x16x32_bf16(af1, bfr, z, 0, 0, 0);
        if (col < 8) {
            #pragma unroll
            for (int q = 0; q < 4; ++q) {
                spart[wslot][rb + q][col] = s0[q];
                spart[wslot][16 + rb + q][col] = s1v[q];
            }
        }
    }

    // transposed, coalesced hT write: hT[b][o][n]
    const int bb = m0 >> 10, nbase = m0 & 1023;
    const int ol = lane >> 1, nh = lane & 1;
    unsigned short vv[16];
    #pragma unroll
    for (int q2 = 0; q2 < 16; ++q2) vv[q2] = tls[wslot][nh * 16 + q2][ol];
    u16x8 lo, hi;
    #pragma unroll
    for (int q2 = 0; q2 < 8; ++q2) { lo[q2] = vv[q2]; hi[q2] = vv[8 + q2]; }
    unsigned short* dst = hT + ((size_t)(bb * D_ + n0 + ol)) * N_ + nbase + nh * 16;
    *(u16x8*)dst = lo;
    *(u16x8*)(dst + 8) = hi;

    __syncthreads();
    // reduce s partials across 8 waves, write s1/s2
    if (tid < 256) {
        const int row = tid >> 3, s = tid & 7;
        float v = 0.f;
        #pragma unroll
        for (int wv = 0; wv < 8; ++wv) v += spart[wv][row][s];
        if (s < 4) s1[s * M_ + m0 + row] = v;
        else       s2[(s - 4) * M_ + m0 + row] = v;
    }
}

// ------- fused k34: scores -> exp (LDS, swizzled) -> GEMM with 1/l epilogue --
// 512 thr, grid 256; bid&7 = batch -> reads hT[b] from XCD-b L2 (producer-pinned)
// adj is loaded NON-TEMPORALLY: it is read exactly once, and its 4 MB/XCD stream
// otherwise evicts the 512 KB hT[b] panel from L2 between phase 1 and phase 2,
// turning the phase-2 B-reads (up to 16 MB/XCD) into HBM traffic.
__global__ __launch_bounds__(512) void k_fused(const int* __restrict__ adj,
        const float* __restrict__ s1, const float* __restrict__ s2,
        const unsigned short* __restrict__ hT, float* __restrict__ out) {
    __shared__ unsigned short Pe[32 * 1024];   // 64 KB, XOR-swizzled rows
    __shared__ float invl[32];
    const int b  = blockIdx.x & 7;
    const int i0 = (blockIdx.x >> 3) << 5;
    const int tid = threadIdx.x;

    // phase-2 B pointers; prefetch iter-0/1 fragments (independent of phase 1)
    const int w = tid >> 6, lane = tid & 63;
    const int r = lane & 15, kg = lane >> 4;
    const int o0 = w << 5;
    const unsigned short* hTb = hT + (((size_t)b) << 18);
    const unsigned short* pb0 = hTb + (o0 + r) * N_ + kg * 8;
    const unsigned short* pb1 = pb0 + 16 * N_;
    bf16x8 c00 = *(const bf16x8*)pb0;
    bf16x8 c10 = *(const bf16x8*)pb1;
    bf16x8 c01 = *(const bf16x8*)(pb0 + 32);
    bf16x8 c11 = *(const bf16x8*)(pb1 + 32);

    // ---- phase 1: e = [adj!=0] * exp(att), 16 threads/row, depth-1 prefetch -
    {
        const int ir = tid >> 4, tj = tid & 15;
        const int i = i0 + ir;
        const int gr = b * N_ + i;
        const float s1i0 = s1[0 * M_ + gr], s1i1 = s1[1 * M_ + gr];
        const float s1i2 = s1[2 * M_ + gr], s1i3 = s1[3 * M_ + gr];
        // zones: j<512 | 512..767 | >=768 ; ko<0 means "no mask" (score 0)
        float zbA, zbB, zbC; int koA, koB, koC;
        if (i < 512)      { zbA = 0.f;  koA = -1;     zbB = s1i2; koB = 2 * M_; zbC = s1i3; koC = 3 * M_; }
        else if (i < 768) { zbA = s1i2; koA = 2 * M_; zbB = s1i1; koB = 1 * M_; zbC = 0.f;  koC = -1;     }
        else              { zbA = s1i3; koA = 3 * M_; zbB = 0.f;  koB = -1;     zbC = 0.f;  koC = -1;     }
        float dval; { float t = s1i0 + s2[b * N_ + i]; dval = fmaxf(t, 0.2f * t); }
        const int* arow = adj + (size_t)gr * N_;
        const float* s2b = s2 + b * N_;
        float cbase[8]; int cko[8];
        #pragma unroll
        for (int c = 0; c < 8; ++c) {
            cbase[c] = c < 4 ? zbA : (c < 6 ? zbB : zbC);
            cko[c]   = c < 4 ? koA : (c < 6 ? koB : koC);
        }
        float lsum = 0.f;
        // prefetch chunk 0 (adj: non-temporal, zero-reuse stream)
        i32x4 pa0 = __builtin_nontemporal_load((const i32x4*)(arow + tj * 8));
        i32x4 pa1 = __builtin_nontemporal_load((const i32x4*)(arow + tj * 8) + 1);
        const float* sp0 = s2b + (cko[0] < 0 ? 0 : cko[0]) + tj * 8;
        float4 pv0 = *(const float4*)sp0;
        float4 pv1 = *(const float4*)(sp0 + 4);
        #pragma unroll
        for (int c = 0; c < 8; ++c) {
            const int j0 = c * 128 + tj * 8;   // zone uniform per c
            const float base = cbase[c]; const int ko = cko[c];
            const i32x4 a0 = pa0, a1v = pa1;
            const float4 v0 = pv0, v1 = pv1;
            if (c < 7) {
                const int j0n = (c + 1) * 128 + tj * 8;
                pa0 = __builtin_nontemporal_load((const i32x4*)(arow + j0n));
                pa1 = __builtin_nontemporal_load((const i32x4*)(arow + j0n) + 1);
                const float* sp = s2b + (cko[c + 1] < 0 ? 0 : cko[c + 1]) + j0n;
                pv0 = *(const float4*)sp; pv1 = *(const float4*)(sp + 4);
            }
            const float sv[8] = {v0.x, v0.y, v0.z, v0.w, v1.x, v1.y, v1.z, v1.w};
            const int   av[8] = {a0[0], a0[1], a0[2], a0[3], a1v[0], a1v[1], a1v[2], a1v[3]};
            float evv[8];
            #pragma unroll
            for (int q = 0; q < 8; ++q) {
                const int j = j0 + q;
                float att;
                if (ko >= 0) { float t = base + sv[q]; att = fmaxf(t, 0.2f * t); }
                else att = 0.f;
                if (j == i) att = dval;
                const float ev = (av[q] == 0) ? 0.f : __expf(att);
                lsum += ev;
                evv[q] = ev;
            }
            union { unsigned int u4[4]; u16x8 v8; } c8;
            c8.u4[0] = cvtpk(evv[0], evv[1]); c8.u4[1] = cvtpk(evv[2], evv[3]);
            c8.u4[2] = cvtpk(evv[4], evv[5]); c8.u4[3] = cvtpk(evv[6], evv[7]);
            *(u16x8*)((char*)Pe + ((ir * 2048 + j0 * 2) ^ ((ir & 7) << 4))) = c8.v8;
        }
        lsum += __shfl_xor(lsum, 1, 64);
        lsum += __shfl_xor(lsum, 2, 64);
        lsum += __shfl_xor(lsum, 4, 64);
        lsum += __shfl_xor(lsum, 8, 64);
        if (tj == 0) invl[ir] = 1.f / lsum;
    }
    __syncthreads();

    // ---- phase 2: out = elu((Pe @ h) * invl), depth-2 B prefetch ----------
    f32x4 z = {0.f, 0.f, 0.f, 0.f};
    f32x4 acc00 = z, acc01 = z, acc10 = z, acc11 = z;
    const char* Pc = (const char*)Pe;
    const int sw0 = (r & 7) << 4;
    const int base0 = r * 2048, base1 = (16 + r) * 2048;
    #pragma unroll 2
    for (int k0 = 0; k0 < N_; k0 += 64) {
        // half 1: consume c00/c10 (k0), prefetch k0+64
        int kb = (k0 + kg * 8) * 2;
        bf16x8 a0 = *(const bf16x8*)(Pc + ((base0 + kb) ^ sw0));
        bf16x8 a1f = *(const bf16x8*)(Pc + ((base1 + kb) ^ sw0));
        bf16x8 b0 = c00, b1 = c10;
        if (k0 + 64 < N_) {
            c00 = *(const bf16x8*)(pb0 + k0 + 64);
            c10 = *(const bf16x8*)(pb1 + k0 + 64);
        }
        acc00 = __builtin_amdgcn_mfma_f32_16x16x32_bf16(a0, b0, acc00, 0, 0, 0);
        acc01 = __builtin_amdgcn_mfma_f32_16x16x32_bf16(a0, b1, acc01, 0, 0, 0);
        acc10 = __builtin_amdgcn_mfma_f32_16x16x32_bf16(a1f, b0, acc10, 0, 0, 0);
        acc11 = __builtin_amdgcn_mfma_f32_16x16x32_bf16(a1f, b1, acc11, 0, 0, 0);
        // half 2: consume c01/c11 (k0+32), prefetch k0+96
        kb = (k0 + 32 + kg * 8) * 2;
        a0 = *(const bf16x8*)(Pc + ((base0 + kb) ^ sw0));
        a1f = *(const bf16x8*)(Pc + ((base1 + kb) ^ sw0));
        b0 = c01; b1 = c11;
        if (k0 + 96 < N_) {
            c01 = *(const bf16x8*)(pb0 + k0 + 96);
            c11 = *(const bf16x8*)(pb1 + k0 + 96);
        }
        acc00 = __builtin_amdgcn_mfma_f32_16x16x32_bf16(a0, b0, acc00, 0, 0, 0);
        acc01 = __builtin_amdgcn_mfma_f32_16x16x32_bf16(a0, b1, acc01, 0, 0, 0);
        acc10 = __builtin_amdgcn_mfma_f32_16x16x32_bf16(a1f, b0, acc10, 0, 0, 0);
        acc11 = __builtin_amdgcn_mfma_f32_16x16x32_bf16(a1f, b1, acc11, 0, 0, 0);
    }
    const int col = lane & 15, rb = (lane >> 4) << 2;
    f32x4 accs[2][2] = {{acc00, acc01}, {acc10, acc11}};
    #pragma unroll
    for (int rt = 0; rt < 2; ++rt) {
        #pragma unroll
        for (int q = 0; q < 4; ++q) {
            const int il = rt * 16 + rb + q;
            const float sc = invl[il];
            #pragma unroll
            for (int ct = 0; ct < 2; ++ct) {
                float v = accs[rt][ct][q] * sc;
                v = v > 0.f ? v : (__expf(v) - 1.f);   // elu
                // NT store: out is written once, never re-read -> keep hT in L2
                __builtin_nontemporal_store(v,
                    &out[((size_t)(b * N_ + i0 + il)) * D_ + o0 + ct * 16 + col]);
            }
        }
    }
}

extern "C" void kernel_launch(void* const* d_in, const int* in_sizes, int n_in,
                              void* d_out, int out_size, void* d_ws, size_t ws_size,
                              hipStream_t stream) {
    const float* x   = (const float*)d_in[0];
    const int*   adj = (const int*)d_in[1];
    const float* W   = (const float*)d_in[2];
    const float* a1  = (const float*)d_in[3];
    const float* a2  = (const float*)d_in[4];
    float* out = (float*)d_out;

    char* ws = (char*)d_ws;
    unsigned short* hT = (unsigned short*)ws;                     // 4 MB  h bf16 [b][o][n]
    float* s1 = (float*)(ws + (4u << 20));                        // 128 KB
    float* s2 = (float*)(ws + (4u << 20) + (128u << 10));         // 128 KB

    hipLaunchKernelGGL(k_hgemm, dim3(256), dim3(512), 0, stream, x, W, a1, a2, hT, s1, s2);
    hipLaunchKernelGGL(k_fused, dim3(256), dim3(512), 0, stream, adj, s1, s2, hT, out);
}